// Round 8
// baseline (144.314 us; speedup 1.0000x reference)
//
#include <hip/hip_runtime.h>

// Causal quadratic linear attention, chunked-scan, SINGLE fused kernel.
//   (q.k)^2 = sum_{i,j} q_i q_j k_i k_j   (256 ordered-pair features, f = 16i+j)
// CHUNK=128, NCHUNK=32. Grid 256 = (h = bid&7, c = bid>>3), 512 thr (8 waves).
// Phase A: stage K (Ktf f32 + Kl bf16) and V (Vt2 bf16) in LDS; MFMA chunk
//          state G[h][c] (operand-swapped); write G (only global intermediate).
//          Device-wide sense barrier (all 256 blocks co-resident: 64KB LDS,
//          512 thr -> >=1 block/CU capacity each on 256 CUs).
// Phase B: exclusive prefix sum_{cc<c} G[h][cc] -> LDS Hlds (f32 regs, bf16).
// Phase C: 8 waves x 16 queries: state apply from Hlds + intra-chunk causal
//          tiles from Kl/Vt2 (V permutation applied at read time, 2x b64).
// LDS swizzles: byte ^= (row&7)<<4 (512B/256B strides); Kl: ^= (key&1)<<4.

#define SEQN 4096
#define NHEAD 8
#define DKEY 16
#define DVAL 64
#define CHUNK 128
#define NCHUNK 32
#define ALPHA 0.03125f

typedef float f32x4 __attribute__((ext_vector_type(4)));
typedef __bf16 bf16x4 __attribute__((ext_vector_type(4)));
typedef __bf16 bf16x8 __attribute__((ext_vector_type(8)));
typedef unsigned long long u64;
typedef u64 u64x2 __attribute__((ext_vector_type(2)));

#define SW512(row, colb) (((row) << 9) + ((colb) ^ (((row) & 7) << 4)))
#define SW256(row, colb) (((row) << 8) + ((colb) ^ (((row) & 7) << 4)))

__device__ inline float bf2f(__bf16 x) {
    unsigned short u = __builtin_bit_cast(unsigned short, x);
    unsigned int v = ((unsigned int)u) << 16;
    return __builtin_bit_cast(float, v);
}

__global__ __launch_bounds__(512, 1)
void fused_all(const float* __restrict__ Qg, const float* __restrict__ Kg,
               const float* __restrict__ Vg, float* __restrict__ Og,
               __bf16* __restrict__ G, unsigned* __restrict__ bar)
{
    __shared__ __align__(128) unsigned char sVt2[80 * 256];   // bf16 [80][128] swz (20KB)
    __shared__ __align__(128) unsigned char sKl[128 * 32];    // bf16 [128][16] swz (4KB)
    __shared__ __align__(128) unsigned char sU[80 * 512];     // A: Ktf f32[16][128] swz; B/C: Hlds bf16[80][256] swz (40KB)

    const int tid = threadIdx.x;
    const int w = tid >> 6;          // wave 0..7
    const int lane = tid & 63;
    const int r = lane & 15, g = lane >> 4;
    const int bid = blockIdx.x;
    const int h = bid & 7, c = bid >> 3;   // c: 0..31
    const int k0 = c * CHUNK;

    // ================= Phase A =================
    // stage K: thread (key = tid>>2, part = tid&3)
    {
        const int key = tid >> 2, part = tid & 3;
        const float* kp = Kg + ((size_t)h * SEQN + k0 + key) * DKEY + 4 * part;
        const f32x4 a = *(const f32x4*)kp;
        #pragma unroll
        for (int j = 0; j < 4; ++j)
            *(float*)(sU + SW512(4 * part + j, key * 4)) = a[j];
        bf16x4 o;
        #pragma unroll
        for (int j = 0; j < 4; ++j) o[j] = (__bf16)a[j];
        *(bf16x4*)(sKl + key * 32 + ((8 * part) ^ ((key & 1) << 4))) = o;
    }
    // stage V rows 0..63 (dim el, cols t, swz)
    {
        const int el = tid & 63;
        const int seg = tid >> 6;
        const float* __restrict__ Vh = Vg + (size_t)h * SEQN * DVAL;
        #pragma unroll
        for (int p = 0; p < 2; ++p) {
            const int tb = 8 * (seg + 8 * p);    // 0..120
            bf16x8 v;
            #pragma unroll
            for (int j = 0; j < 8; ++j)
                v[j] = (__bf16)Vh[(size_t)(k0 + tb + j) * DVAL + el];
            *(bf16x8*)(sVt2 + SW256(el, tb * 2)) = v;
        }
    }
    // rows 64..79: ones (row 64) / zeros
    {
        const int row = 64 + (tid >> 5);
        const int i = tid & 31;
        const u64 val = (row == 64) ? 0x3F803F803F803F80ULL : 0ULL;
        *(u64*)(sVt2 + SW256(row, 8 * i)) = val;
    }
    __syncthreads();

    // MFMA: G[e][f]; wave w owns f-tiles 2w, 2w+1 (operand-swapped)
    {
        f32x4 acc[2][5] = {};
        #pragma unroll
        for (int ks = 0; ks < 4; ++ks) {
            const int t0 = 32 * ks + 8 * g;
            bf16x8 af[5];
            #pragma unroll
            for (int et = 0; et < 5; ++et)
                af[et] = *(const bf16x8*)(sVt2 + SW256(16 * et + r, t0 * 2));
            const f32x4 kra = *(const f32x4*)(sU + SW512(r, t0 * 4));
            const f32x4 krb = *(const f32x4*)(sU + SW512(r, t0 * 4 + 16));
            #pragma unroll
            for (int fa = 0; fa < 2; ++fa) {
                const int ft = 2 * w + fa;
                const f32x4 kfa = *(const f32x4*)(sU + SW512(ft, t0 * 4));
                const f32x4 kfb = *(const f32x4*)(sU + SW512(ft, t0 * 4 + 16));
                bf16x8 bfrag;
                #pragma unroll
                for (int j = 0; j < 4; ++j) {
                    bfrag[j]     = (__bf16)(kfa[j] * kra[j]);
                    bfrag[4 + j] = (__bf16)(kfb[j] * krb[j]);
                }
                #pragma unroll
                for (int et = 0; et < 5; ++et)
                    acc[fa][et] = __builtin_amdgcn_mfma_f32_16x16x32_bf16(
                        bfrag, af[et], acc[fa][et], 0, 0, 0);
            }
        }
        __bf16* Gc = G + (size_t)((h * NCHUNK + c) * 80) * 256;
        #pragma unroll
        for (int fa = 0; fa < 2; ++fa) {
            const int fb = 16 * (2 * w + fa) + 4 * g;
            #pragma unroll
            for (int et = 0; et < 5; ++et) {
                bf16x4 o;
                #pragma unroll
                for (int i = 0; i < 4; ++i) o[i] = (__bf16)acc[fa][et][i];
                *(bf16x4*)&Gc[(size_t)(16 * et + r) * 256 + fb] = o;
            }
        }
    }

    // ================= device-wide barrier =================
    __threadfence();        // release: G stores visible device-wide
    __syncthreads();
    if (tid == 0) {
        const unsigned arrived = atomicAdd(&bar[0], 1u);
        if (arrived == 255u) {
            __hip_atomic_store(&bar[1], 1u, __ATOMIC_RELEASE, __HIP_MEMORY_SCOPE_AGENT);
        } else {
            while (__hip_atomic_load(&bar[1], __ATOMIC_ACQUIRE, __HIP_MEMORY_SCOPE_AGENT) == 0u)
                __builtin_amdgcn_s_sleep(8);
        }
    }
    __syncthreads();
    __threadfence();        // acquire: other blocks' G stores visible

    // ================= Phase B: exclusive prefix -> Hlds =================
    if (c > 0) {
        float facc[40] = {};
        for (int cc = 0; cc < c; ++cc) {
            const __bf16* Gc = G + (size_t)((h * NCHUNK + cc) * 80) * 256;
            #pragma unroll
            for (int k2 = 0; k2 < 5; ++k2) {
                const bf16x8 v = *(const bf16x8*)&Gc[8 * tid + 4096 * k2];
                #pragma unroll
                for (int j = 0; j < 8; ++j) facc[8 * k2 + j] += bf2f(v[j]);
            }
        }
        #pragma unroll
        for (int k2 = 0; k2 < 5; ++k2) {
            const int fid = 8 * tid + 4096 * k2;
            const int row = fid >> 8;
            const int colb = (fid & 255) * 2;
            bf16x8 o;
            #pragma unroll
            for (int j = 0; j < 8; ++j) o[j] = (__bf16)facc[8 * k2 + j];
            *(bf16x8*)(sU + SW512(row, colb)) = o;
        }
        __syncthreads();
    }

    // ================= Phase C: state apply + intra =================
    const int qb = c * CHUNK + 16 * w;
    float qr[16];
    {
        const float* qp = Qg + ((size_t)h * SEQN + qb + r) * DKEY;
        #pragma unroll
        for (int m = 0; m < 4; ++m) {
            const f32x4 v = *(const f32x4*)(qp + 4 * m);
            qr[4 * m + 0] = v[0]; qr[4 * m + 1] = v[1];
            qr[4 * m + 2] = v[2]; qr[4 * m + 3] = v[3];
        }
    }
    float qsel[8];
    #pragma unroll
    for (int j = 0; j < 8; ++j) qsel[j] = (g & 1) ? qr[8 + j] : qr[j];
    bf16x8 qfrag = {};
    if (g < 2) {
        #pragma unroll
        for (int j = 0; j < 8; ++j) qfrag[j] = (__bf16)qsel[j];
    }

    f32x4 oacc[4] = {};
    f32x4 zacc4 = {};
    float zin = 0.f;

    if (c > 0) {
        #pragma unroll
        for (int ks = 0; ks < 8; ++ks) {
            const int t0 = 32 * ks + 8 * g;
            bf16x8 af[4];
            #pragma unroll
            for (int dt = 0; dt < 4; ++dt)
                af[dt] = *(const bf16x8*)(sU + SW512(16 * dt + r, t0 * 2));
            const bf16x8 afz = *(const bf16x8*)(sU + SW512(64 + r, t0 * 2));
            const float qi = ALPHA * ((g & 2) ? qr[2 * ks + 1] : qr[2 * ks]);
            bf16x8 pf;
            #pragma unroll
            for (int j = 0; j < 8; ++j) pf[j] = (__bf16)(qi * qsel[j]);
            #pragma unroll
            for (int dt = 0; dt < 4; ++dt)
                oacc[dt] = __builtin_amdgcn_mfma_f32_16x16x32_bf16(af[dt], pf, oacc[dt], 0, 0, 0);
            zacc4 = __builtin_amdgcn_mfma_f32_16x16x32_bf16(afz, pf, zacc4, 0, 0, 0);
        }
    }

    // intra-chunk causal tiles from LDS (Kl + Vt2, permuted at read)
    const int qG = qb + r;
    const int smax = w >> 1;    // include 32-key subtiles 2tl+ks <= smax
    #pragma unroll
    for (int tl = 0; tl < 2; ++tl) {
        #pragma unroll
        for (int ks = 0; ks < 2; ++ks) {
            const int sidx = 2 * tl + ks;
            if (sidx <= smax) {
                const bool diag = (sidx == smax);
                // K frags
                bf16x8 kf[2];
                #pragma unroll
                for (int uk = 0; uk < 2; ++uk) {
                    bf16x8 f = {};
                    if (g < 2) {
                        const int key = 64 * tl + 32 * ks + 16 * uk + r;
                        f = *(const bf16x8*)(sKl + key * 32 + ((16 * g) ^ ((key & 1) << 4)));
                    }
                    kf[uk] = f;
                }
                const f32x4 zero4 = {};
                f32x4 s[2];
                #pragma unroll
                for (int uk = 0; uk < 2; ++uk)
                    s[uk] = __builtin_amdgcn_mfma_f32_16x16x32_bf16(kf[uk], qfrag, zero4, 0, 0, 0);

                bf16x8 pf;
                float zs = 0.f;
                const int k0g = k0 + 64 * tl + 32 * ks;
                #pragma unroll
                for (int uk = 0; uk < 2; ++uk) {
                    const int kGb = k0g + 16 * uk + 4 * g;
                    #pragma unroll
                    for (int i = 0; i < 4; ++i) {
                        const float sv = s[uk][i];
                        float p = ALPHA * sv * sv;
                        if (diag && (kGb + i > qG)) p = 0.f;
                        zs += p;
                        pf[4 * uk + i] = (__bf16)p;
                    }
                }
                zin += zs;
                // V frags: two b64 units per dt (uk=0: unit 16tl+8ks+g, uk=1: +4)
                #pragma unroll
                for (int dt = 0; dt < 4; ++dt) {
                    const int base = 128 * tl + 64 * ks + 8 * g;
                    u64x2 both;
                    both[0] = *(const u64*)(sVt2 + SW256(16 * dt + r, base));
                    both[1] = *(const u64*)(sVt2 + SW256(16 * dt + r, base + 32));
                    const bf16x8 vf = __builtin_bit_cast(bf16x8, both);
                    oacc[dt] = __builtin_amdgcn_mfma_f32_16x16x32_bf16(vf, pf, oacc[dt], 0, 0, 0);
                }
            }
        }
    }

    // stores
    const int q = qb + r;
    #pragma unroll
    for (int dt = 0; dt < 4; ++dt) {
        float* op = Og + ((size_t)h * SEQN + q) * DVAL + 16 * dt + 4 * g;
        *(f32x4*)op = oacc[dt];
    }
    zin += __shfl_xor(zin, 16); zin += __shfl_xor(zin, 32);
    if (lane < 16) {
        float* zp = Og + (size_t)NHEAD * SEQN * DVAL + (size_t)h * SEQN + qb;
        zp[r] = zin + zacc4[0];
    }
}

// ---------------- Fallback (monolithic) if workspace too small ----------------
__global__ __launch_bounds__(128, 2)
void taylor_mono(const float* __restrict__ Qg, const float* __restrict__ Kg,
                 const float* __restrict__ Vg, float* __restrict__ Og)
{
    __shared__ __align__(16) __bf16 Kl[64 * 32];
    __shared__ __align__(16) __bf16 Vt[64 * 72];
    typedef __bf16 bf16x2 __attribute__((ext_vector_type(2)));
    const int tid = threadIdx.x;
    const int wv = tid >> 6;
    const int lane = tid & 63;
    const int r = lane & 15, g = lane >> 4;
    const int bid = blockIdx.x;
    const int h = bid & 7;
    const int tt = bid >> 3;
    const int qt = (tt & 1) ? (tt >> 1) : (63 - (tt >> 1));
    const int qb = qt * 64 + wv * 32;
    const float* __restrict__ Qh = Qg + (size_t)h * SEQN * DKEY;
    const float* __restrict__ Kh = Kg + (size_t)h * SEQN * DKEY;
    const float* __restrict__ Vh = Vg + (size_t)h * SEQN * DVAL;
    for (int row = tid; row < 64; row += 128) {
        bf16x8 z = {};
        *(bf16x8*)&Kl[row * 32 + 16] = z;
        *(bf16x8*)&Kl[row * 32 + 24] = z;
    }
    bf16x8 qfrag[2];
    #pragma unroll
    for (int uq = 0; uq < 2; ++uq) {
        bf16x8 f = {};
        if (g < 2) {
            const float* qp = Qh + (size_t)(qb + 16 * uq + r) * DKEY + 8 * g;
            const f32x4 a = *(const f32x4*)qp;
            const f32x4 b = *(const f32x4*)(qp + 4);
            #pragma unroll
            for (int j = 0; j < 4; ++j) { f[j] = (__bf16)a[j]; f[4 + j] = (__bf16)b[j]; }
        }
        qfrag[uq] = f;
    }
    f32x4 oacc[2][4] = {};
    float zacc0 = 0.f, zacc1 = 0.f;
    const int nkt = qt + 1;
    for (int kt = 0; kt < nkt; ++kt) {
        const int k0 = kt * 64;
        {
            const int key = tid >> 1, half = tid & 1;
            const float* kp = Kh + (size_t)(k0 + key) * DKEY + 8 * half;
            const f32x4 a = *(const f32x4*)kp;
            const f32x4 b = *(const f32x4*)(kp + 4);
            bf16x8 kb;
            #pragma unroll
            for (int j = 0; j < 4; ++j) { kb[j] = (__bf16)a[j]; kb[4 + j] = (__bf16)b[j]; }
            *(bf16x8*)&Kl[key * 32 + 8 * half] = kb;
        }
        {
            const int d = tid & 63;
            const int kp2 = (tid >> 6) * 2;
            #pragma unroll
            for (int i = 0; i < 16; ++i) {
                const int kk = i * 4 + kp2;
                const float a0 = Vh[(size_t)(k0 + kk) * DVAL + d];
                const float a1 = Vh[(size_t)(k0 + kk + 1) * DVAL + d];
                const int w32 = kk & 31;
                const int col = (kk & 32) + ((w32 >> 2) & 3) * 8 + ((w32 >> 4) << 2) + (kk & 3);
                bf16x2 p; p[0] = (__bf16)a0; p[1] = (__bf16)a1;
                *(bf16x2*)&Vt[d * 72 + col] = p;
            }
        }
        __syncthreads();
        const bool diag = (kt + 1 == nkt);
        #pragma unroll
        for (int ks = 0; ks < 2; ++ks) {
            if (k0 + 32 * ks < qb + 32) {
                bf16x8 vfrag[4];
                #pragma unroll
                for (int dt = 0; dt < 4; ++dt)
                    vfrag[dt] = *(const bf16x8*)&Vt[(16 * dt + r) * 72 + 32 * ks + 8 * g];
                bf16x8 kfr[2];
                #pragma unroll
                for (int uk = 0; uk < 2; ++uk)
                    kfr[uk] = *(const bf16x8*)&Kl[(32 * ks + 16 * uk + r) * 32 + 8 * g];
                const f32x4 zero4 = {};
                f32x4 s[2][2];
                #pragma unroll
                for (int uq = 0; uq < 2; ++uq)
                    #pragma unroll
                    for (int uk = 0; uk < 2; ++uk)
                        s[uq][uk] = __builtin_amdgcn_mfma_f32_16x16x32_bf16(
                            kfr[uk], qfrag[uq], zero4, 0, 0, 0);
                #pragma unroll
                for (int uq = 0; uq < 2; ++uq) {
                    bf16x8 pf;
                    float zs = 0.f;
                    #pragma unroll
                    for (int uk = 0; uk < 2; ++uk) {
                        const int kGb = k0 + 32 * ks + 16 * uk + 4 * g;
                        const int qG = qb + 16 * uq + r;
                        #pragma unroll
                        for (int i = 0; i < 4; ++i) {
                            const float sv = s[uq][uk][i];
                            float p = 0.03125f * sv * sv;
                            if (diag && (kGb + i > qG)) p = 0.f;
                            zs += p;
                            pf[4 * uk + i] = (__bf16)p;
                        }
                    }
                    if (uq == 0) zacc0 += zs; else zacc1 += zs;
                    #pragma unroll
                    for (int dt = 0; dt < 4; ++dt)
                        oacc[uq][dt] = __builtin_amdgcn_mfma_f32_16x16x32_bf16(
                            vfrag[dt], pf, oacc[uq][dt], 0, 0, 0);
                }
            }
        }
        __syncthreads();
    }
    #pragma unroll
    for (int uq = 0; uq < 2; ++uq) {
        const int q = qb + 16 * uq + r;
        #pragma unroll
        for (int dt = 0; dt < 4; ++dt) {
            float* op = Og + ((size_t)h * SEQN + q) * DVAL + 16 * dt + 4 * g;
            *(f32x4*)op = oacc[uq][dt];
        }
    }
    zacc0 += __shfl_xor(zacc0, 16); zacc0 += __shfl_xor(zacc0, 32);
    zacc1 += __shfl_xor(zacc1, 16); zacc1 += __shfl_xor(zacc1, 32);
    if (lane < 16) {
        float* zp = Og + (size_t)NHEAD * SEQN * DVAL + (size_t)h * SEQN + qb;
        zp[r] = zacc0;
        zp[16 + r] = zacc1;
    }
}

extern "C" void kernel_launch(void* const* d_in, const int* in_sizes, int n_in,
                              void* d_out, int out_size, void* d_ws, size_t ws_size,
                              hipStream_t stream) {
    const float* Q = (const float*)d_in[0];
    const float* K = (const float*)d_in[1];
    const float* V = (const float*)d_in[2];
    float* O = (float*)d_out;

    const size_t G_OFF   = 0;              // 8*32*80*256 bf16 = 10,485,760 B
    const size_t BAR_OFF = 10485760;       // 64 B barrier state
    const size_t NEED    = 10485824;

    if (ws_size >= NEED) {
        char* ws = (char*)d_ws;
        __bf16* G = (__bf16*)(ws + G_OFF);
        unsigned* bar = (unsigned*)(ws + BAR_OFF);
        hipMemsetAsync((void*)bar, 0, 64, stream);
        fused_all<<<dim3(256), dim3(512), 0, stream>>>(Q, K, V, O, G, bar);
    } else {
        taylor_mono<<<dim3(512), dim3(128), 0, stream>>>(Q, K, V, O);
    }
}

// Round 9
// 33.285 us; speedup vs baseline: 4.3357x; 4.3357x over previous
//
#include <hip/hip_runtime.h>

// Causal quadratic linear attention, chunked-scan formulation.
//   (q.k)^2 = sum_{i,j} q_i q_j k_i k_j   (256 ordered-pair features, f = 16i+j)
// CHUNK=128, NCHUNK=32. TWO launches:
// p01: convert K/V -> bf16 (Kbf, permuted-transposed Vtg) + per-chunk state
//      G[h][c][e][f] via operand-swapped MFMA. 256 blocks x 512 thr.
// p3m: per (h,c) block (256 x 512 thr): compute exclusive prefix
//      sum_{cc<c} G[h][cc] in registers (XCD-pinned L2 reads) -> swizzled LDS;
//      8 waves x 16 queries: state apply + intra-chunk causal tiles
//      (K/V fragments prefetched from Kbf/Vtg before the prefix loop).
// LDS: power-of-2 row strides + XOR swizzle (byte ^= (row&7)<<4).

#define SEQN 4096
#define NHEAD 8
#define DKEY 16
#define DVAL 64
#define CHUNK 128
#define NCHUNK 32
#define ALPHA 0.03125f

typedef float f32x4 __attribute__((ext_vector_type(4)));
typedef __bf16 bf16x4 __attribute__((ext_vector_type(4)));
typedef __bf16 bf16x8 __attribute__((ext_vector_type(8)));
typedef unsigned long long u64;
typedef u64 u64x2 __attribute__((ext_vector_type(2)));

#define SW512(row, colb) (((row) << 9) + ((colb) ^ (((row) & 7) << 4)))
#define SW256(row, colb) (((row) << 8) + ((colb) ^ (((row) & 7) << 4)))

__device__ inline float bf2f(__bf16 x) {
    unsigned short u = __builtin_bit_cast(unsigned short, x);
    unsigned int v = ((unsigned int)u) << 16;
    return __builtin_bit_cast(float, v);
}

// ---------------- Phase 01: convert + per-chunk state ----------------
// grid 256 = (h = bid&7, c = bid>>3), 512 thr (8 waves).
__global__ __launch_bounds__(512, 1)
void p01_state(const float* __restrict__ Kg, const float* __restrict__ Vg,
               __bf16* __restrict__ Kbf, __bf16* __restrict__ Vtg,
               __bf16* __restrict__ G)
{
    __shared__ __align__(128) unsigned char Vt2[80 * 256];   // bf16 [80][128], swz
    __shared__ __align__(128) unsigned char Ktf[16 * 512];   // f32  [16][128], swz
    const int tid = threadIdx.x;
    const int w = tid >> 6;          // wave 0..7
    const int lane = tid & 63;
    const int r = lane & 15, g = lane >> 4;
    const int bid = blockIdx.x;
    const int h = bid & 7, c = bid >> 3;              // c: 0..31
    const int k0 = c * CHUNK;

    // ---- stage K transposed (swz) + write Kbf: key = tid>>2, part = tid&3 ----
    {
        const int key = tid >> 2, part = tid & 3;
        const float* kp = Kg + ((size_t)h * SEQN + k0 + key) * DKEY + 4 * part;
        const f32x4 a = *(const f32x4*)kp;
        #pragma unroll
        for (int j = 0; j < 4; ++j)
            *(float*)(Ktf + SW512(4 * part + j, key * 4)) = a[j];
        bf16x4 o;
        #pragma unroll
        for (int j = 0; j < 4; ++j) o[j] = (__bf16)a[j];
        *(bf16x4*)&Kbf[((size_t)h * SEQN + k0 + key) * DKEY + 4 * part] = o;
    }
    // ---- stage V rows 0..63 (dim el, cols t, swz): seg = tid>>6 (0..7) ----
    {
        const int el = tid & 63;
        const int seg = tid >> 6;
        const float* __restrict__ Vh = Vg + (size_t)h * SEQN * DVAL;
        #pragma unroll
        for (int p = 0; p < 2; ++p) {
            const int tb = 8 * (seg + 8 * p);    // 0..120
            bf16x8 v;
            #pragma unroll
            for (int j = 0; j < 8; ++j)
                v[j] = (__bf16)Vh[(size_t)(k0 + tb + j) * DVAL + el];
            *(bf16x8*)(Vt2 + SW256(el, tb * 2)) = v;
        }
    }
    // ---- rows 64..79: ones (row 64) / zeros, one u64 per thread ----
    {
        const int row = 64 + (tid >> 5);
        const int i = tid & 31;
        const u64 val = (row == 64) ? 0x3F803F803F803F80ULL : 0ULL;
        *(u64*)(Vt2 + SW256(row, 8 * i)) = val;
    }
    __syncthreads();

    // ---- Vtg write-out: permuted V^T (static u64-granular permutation) ----
    #pragma unroll
    for (int uu = 0; uu < 2; ++uu) {
        const int unit = 2 * tid + uu;
        const int m = unit & 3;
        const int hsel = (unit >> 2) & 1;
        const int ktl = (unit >> 3) & 1;
        const int dloc = unit >> 4;
        const u64 t0v = *(const u64*)(Vt2 + SW256(dloc, 128 * ktl + 64 * hsel + 8 * m));
        const u64 t1v = *(const u64*)(Vt2 + SW256(dloc, 128 * ktl + 64 * hsel + 8 * m + 32));
        __bf16* vo = Vtg + ((size_t)((h * 64 + 2 * c + ktl) * 64 + dloc)) * 64 + hsel * 32;
        u64x2 pp; pp[0] = t0v; pp[1] = t1v;
        *(u64x2*)((u64*)vo + 2 * m) = pp;
    }

    // ---- MFMA: G[e][f]; wave w owns f-tiles 2w, 2w+1 (operand-swapped) ----
    f32x4 acc[2][5] = {};
    #pragma unroll
    for (int ks = 0; ks < 4; ++ks) {
        const int t0 = 32 * ks + 8 * g;
        bf16x8 af[5];
        #pragma unroll
        for (int et = 0; et < 5; ++et)
            af[et] = *(const bf16x8*)(Vt2 + SW256(16 * et + r, t0 * 2));
        const f32x4 kra = *(const f32x4*)(Ktf + SW512(r, t0 * 4));
        const f32x4 krb = *(const f32x4*)(Ktf + SW512(r, t0 * 4 + 16));
        #pragma unroll
        for (int fa = 0; fa < 2; ++fa) {
            const int ft = 2 * w + fa;
            const f32x4 kfa = *(const f32x4*)(Ktf + SW512(ft, t0 * 4));
            const f32x4 kfb = *(const f32x4*)(Ktf + SW512(ft, t0 * 4 + 16));
            bf16x8 bfrag;
            #pragma unroll
            for (int j = 0; j < 4; ++j) {
                bfrag[j]     = (__bf16)(kfa[j] * kra[j]);
                bfrag[4 + j] = (__bf16)(kfb[j] * krb[j]);
            }
            #pragma unroll
            for (int et = 0; et < 5; ++et)
                acc[fa][et] = __builtin_amdgcn_mfma_f32_16x16x32_bf16(
                    bfrag, af[et], acc[fa][et], 0, 0, 0);
        }
    }
    // ---- write G[h][c][e][f]: lane writes 4 f-contiguous bf16 (8B) ----
    __bf16* Gc = G + (size_t)((h * NCHUNK + c) * 80) * 256;
    #pragma unroll
    for (int fa = 0; fa < 2; ++fa) {
        const int fb = 16 * (2 * w + fa) + 4 * g;
        #pragma unroll
        for (int et = 0; et < 5; ++et) {
            bf16x4 o;
            #pragma unroll
            for (int i = 0; i < 4; ++i) o[i] = (__bf16)acc[fa][et][i];
            *(bf16x4*)&Gc[(size_t)(16 * et + r) * 256 + fb] = o;
        }
    }
}

// ---------------- Phase 3m: prefix + state apply + intra (merged) ----------------
// grid 256 = (h = bid&7, c = bid>>3), 512 thr (8 waves; wave w: queries 16w..16w+15).

#define LOADKV(KT, KF, VF)                                                        \
    {                                                                             \
        const __bf16* Kb_ = Kbf + ((size_t)h * SEQN + (KT) * 64) * DKEY;          \
        const __bf16* Vb_ = Vtg + (size_t)((h * 64 + (KT)) * 64) * 64;            \
        _Pragma("unroll")                                                         \
        for (int ks_ = 0; ks_ < 2; ++ks_) {                                       \
            _Pragma("unroll")                                                     \
            for (int uk_ = 0; uk_ < 2; ++uk_) {                                   \
                bf16x8 f_ = {};                                                   \
                if (g < 2)                                                        \
                    f_ = *(const bf16x8*)&Kb_[(32 * ks_ + 16 * uk_ + r) * DKEY + 8 * g]; \
                KF[ks_][uk_] = f_;                                                \
            }                                                                     \
            _Pragma("unroll")                                                     \
            for (int dt_ = 0; dt_ < 4; ++dt_)                                     \
                VF[ks_][dt_] = *(const bf16x8*)&Vb_[(size_t)(16 * dt_ + r) * 64 + 32 * ks_ + 8 * g]; \
        }                                                                         \
    }

__global__ __launch_bounds__(512, 1)
void p3m_attend(const float* __restrict__ Qg, const __bf16* __restrict__ Kbf,
                const __bf16* __restrict__ Vtg, const __bf16* __restrict__ G,
                float* __restrict__ Og)
{
    __shared__ __align__(128) unsigned char Hlds[80 * 512];   // bf16 [80][256], swz
    const int tid = threadIdx.x;
    const int lane = tid & 63;
    const int r = lane & 15, g = lane >> 4;
    const int w = tid >> 6;          // wave 0..7
    const int bid = blockIdx.x;
    const int h = bid & 7;
    const int c = bid >> 3;          // 0..31
    const int qb = c * CHUNK + 16 * w;

    // ---- Q row (fp32) ----
    float qr[16];
    {
        const float* qp = Qg + ((size_t)h * SEQN + qb + r) * DKEY;
        #pragma unroll
        for (int m = 0; m < 4; ++m) {
            const f32x4 v = *(const f32x4*)(qp + 4 * m);
            qr[4 * m + 0] = v[0]; qr[4 * m + 1] = v[1];
            qr[4 * m + 2] = v[2]; qr[4 * m + 3] = v[3];
        }
    }
    float qsel[8];
    #pragma unroll
    for (int j = 0; j < 8; ++j) qsel[j] = (g & 1) ? qr[8 + j] : qr[j];
    bf16x8 qfrag = {};
    if (g < 2) {
        #pragma unroll
        for (int j = 0; j < 8; ++j) qfrag[j] = (__bf16)qsel[j];
    }

    // ---- prefetch intra K/V fragments (hidden under prefix loop) ----
    bf16x8 kf0[2][2], vf0[2][4], kf1[2][2], vf1[2][4];
    LOADKV(2 * c, kf0, vf0);
    if (w >= 4) LOADKV(2 * c + 1, kf1, vf1);

    // ---- exclusive prefix sum_{cc<c} G[h][cc] -> Hlds (swz) ----
    if (c > 0) {
        float facc[40] = {};
        for (int cc = 0; cc < c; ++cc) {
            const __bf16* Gc = G + (size_t)((h * NCHUNK + cc) * 80) * 256;
            #pragma unroll
            for (int k2 = 0; k2 < 5; ++k2) {
                const bf16x8 v = *(const bf16x8*)&Gc[8 * tid + 4096 * k2];
                #pragma unroll
                for (int j = 0; j < 8; ++j) facc[8 * k2 + j] += bf2f(v[j]);
            }
        }
        #pragma unroll
        for (int k2 = 0; k2 < 5; ++k2) {
            const int fid = 8 * tid + 4096 * k2;
            const int row = fid >> 8;
            const int colb = (fid & 255) * 2;
            bf16x8 o;
            #pragma unroll
            for (int j = 0; j < 8; ++j) o[j] = (__bf16)facc[8 * k2 + j];
            *(bf16x8*)(Hlds + SW512(row, colb)) = o;
        }
        __syncthreads();
    }

    f32x4 oacc[4] = {};
    f32x4 zacc4 = {};
    float zin = 0.f;

    // ---- state apply from LDS: O += Psi(q) x H_{<c} ----
    if (c > 0) {
        #pragma unroll
        for (int ks = 0; ks < 8; ++ks) {
            const int t0 = 32 * ks + 8 * g;
            bf16x8 af[4];
            #pragma unroll
            for (int dt = 0; dt < 4; ++dt)
                af[dt] = *(const bf16x8*)(Hlds + SW512(16 * dt + r, t0 * 2));
            const bf16x8 afz = *(const bf16x8*)(Hlds + SW512(64 + r, t0 * 2));
            const float qi = ALPHA * ((g & 2) ? qr[2 * ks + 1] : qr[2 * ks]);
            bf16x8 pf;
            #pragma unroll
            for (int j = 0; j < 8; ++j) pf[j] = (__bf16)(qi * qsel[j]);
            #pragma unroll
            for (int dt = 0; dt < 4; ++dt)
                oacc[dt] = __builtin_amdgcn_mfma_f32_16x16x32_bf16(af[dt], pf, oacc[dt], 0, 0, 0);
            zacc4 = __builtin_amdgcn_mfma_f32_16x16x32_bf16(afz, pf, zacc4, 0, 0, 0);
        }
    }

    // ---- intra-chunk causal tiles ----
    const int qG = qb + r;
    const int smax = w >> 1;    // include 32-key subtiles sidx <= smax
    #pragma unroll
    for (int tl = 0; tl < 2; ++tl) {
        #pragma unroll
        for (int ks = 0; ks < 2; ++ks) {
            const int sidx = 2 * tl + ks;
            if (sidx <= smax) {
                const bool diag = (sidx == smax);
                const f32x4 zero4 = {};
                f32x4 s[2];
                #pragma unroll
                for (int uk = 0; uk < 2; ++uk)
                    s[uk] = __builtin_amdgcn_mfma_f32_16x16x32_bf16(
                        (tl == 0) ? kf0[ks][uk] : kf1[ks][uk], qfrag, zero4, 0, 0, 0);
                bf16x8 pf;
                float zs = 0.f;
                const int k0g = c * CHUNK + 64 * tl + 32 * ks;
                #pragma unroll
                for (int uk = 0; uk < 2; ++uk) {
                    const int kGb = k0g + 16 * uk + 4 * g;
                    #pragma unroll
                    for (int i = 0; i < 4; ++i) {
                        const float sv = s[uk][i];
                        float p = ALPHA * sv * sv;
                        if (diag && (kGb + i > qG)) p = 0.f;
                        zs += p;
                        pf[4 * uk + i] = (__bf16)p;
                    }
                }
                zin += zs;
                #pragma unroll
                for (int dt = 0; dt < 4; ++dt)
                    oacc[dt] = __builtin_amdgcn_mfma_f32_16x16x32_bf16(
                        (tl == 0) ? vf0[ks][dt] : vf1[ks][dt], pf, oacc[dt], 0, 0, 0);
            }
        }
    }

    // ---- stores ----
    const int q = qb + r;
    #pragma unroll
    for (int dt = 0; dt < 4; ++dt) {
        float* op = Og + ((size_t)h * SEQN + q) * DVAL + 16 * dt + 4 * g;
        *(f32x4*)op = oacc[dt];
    }
    zin += __shfl_xor(zin, 16); zin += __shfl_xor(zin, 32);
    if (lane < 16) {   // g==0: zacc4[0] holds the e=64 (ones) row for query r
        float* zp = Og + (size_t)NHEAD * SEQN * DVAL + (size_t)h * SEQN + qb;
        zp[r] = zin + zacc4[0];
    }
}

// ---------------- Fallback (monolithic) if workspace too small ----------------
__global__ __launch_bounds__(128, 2)
void taylor_mono(const float* __restrict__ Qg, const float* __restrict__ Kg,
                 const float* __restrict__ Vg, float* __restrict__ Og)
{
    __shared__ __align__(16) __bf16 Kl[64 * 32];
    __shared__ __align__(16) __bf16 Vt[64 * 72];
    typedef __bf16 bf16x2 __attribute__((ext_vector_type(2)));
    const int tid = threadIdx.x;
    const int wv = tid >> 6;
    const int lane = tid & 63;
    const int r = lane & 15, g = lane >> 4;
    const int bid = blockIdx.x;
    const int h = bid & 7;
    const int tt = bid >> 3;
    const int qt = (tt & 1) ? (tt >> 1) : (63 - (tt >> 1));
    const int qb = qt * 64 + wv * 32;
    const float* __restrict__ Qh = Qg + (size_t)h * SEQN * DKEY;
    const float* __restrict__ Kh = Kg + (size_t)h * SEQN * DKEY;
    const float* __restrict__ Vh = Vg + (size_t)h * SEQN * DVAL;
    for (int row = tid; row < 64; row += 128) {
        bf16x8 z = {};
        *(bf16x8*)&Kl[row * 32 + 16] = z;
        *(bf16x8*)&Kl[row * 32 + 24] = z;
    }
    bf16x8 qfrag[2];
    #pragma unroll
    for (int uq = 0; uq < 2; ++uq) {
        bf16x8 f = {};
        if (g < 2) {
            const float* qp = Qh + (size_t)(qb + 16 * uq + r) * DKEY + 8 * g;
            const f32x4 a = *(const f32x4*)qp;
            const f32x4 b = *(const f32x4*)(qp + 4);
            #pragma unroll
            for (int j = 0; j < 4; ++j) { f[j] = (__bf16)a[j]; f[4 + j] = (__bf16)b[j]; }
        }
        qfrag[uq] = f;
    }
    f32x4 oacc[2][4] = {};
    float zacc0 = 0.f, zacc1 = 0.f;
    const int nkt = qt + 1;
    for (int kt = 0; kt < nkt; ++kt) {
        const int k0 = kt * 64;
        {
            const int key = tid >> 1, half = tid & 1;
            const float* kp = Kh + (size_t)(k0 + key) * DKEY + 8 * half;
            const f32x4 a = *(const f32x4*)kp;
            const f32x4 b = *(const f32x4*)(kp + 4);
            bf16x8 kb;
            #pragma unroll
            for (int j = 0; j < 4; ++j) { kb[j] = (__bf16)a[j]; kb[4 + j] = (__bf16)b[j]; }
            *(bf16x8*)&Kl[key * 32 + 8 * half] = kb;
        }
        {
            const int d = tid & 63;
            const int kp2 = (tid >> 6) * 2;
            #pragma unroll
            for (int i = 0; i < 16; ++i) {
                const int kk = i * 4 + kp2;
                const float a0 = Vh[(size_t)(k0 + kk) * DVAL + d];
                const float a1 = Vh[(size_t)(k0 + kk + 1) * DVAL + d];
                const int w32 = kk & 31;
                const int col = (kk & 32) + ((w32 >> 2) & 3) * 8 + ((w32 >> 4) << 2) + (kk & 3);
                bf16x2 p; p[0] = (__bf16)a0; p[1] = (__bf16)a1;
                *(bf16x2*)&Vt[d * 72 + col] = p;
            }
        }
        __syncthreads();
        const bool diag = (kt + 1 == nkt);
        #pragma unroll
        for (int ks = 0; ks < 2; ++ks) {
            if (k0 + 32 * ks < qb + 32) {
                bf16x8 vfrag[4];
                #pragma unroll
                for (int dt = 0; dt < 4; ++dt)
                    vfrag[dt] = *(const bf16x8*)&Vt[(16 * dt + r) * 72 + 32 * ks + 8 * g];
                bf16x8 kfr[2];
                #pragma unroll
                for (int uk = 0; uk < 2; ++uk)
                    kfr[uk] = *(const bf16x8*)&Kl[(32 * ks + 16 * uk + r) * 32 + 8 * g];
                const f32x4 zero4 = {};
                f32x4 s[2][2];
                #pragma unroll
                for (int uq = 0; uq < 2; ++uq)
                    #pragma unroll
                    for (int uk = 0; uk < 2; ++uk)
                        s[uq][uk] = __builtin_amdgcn_mfma_f32_16x16x32_bf16(
                            kfr[uk], qfrag[uq], zero4, 0, 0, 0);
                #pragma unroll
                for (int uq = 0; uq < 2; ++uq) {
                    bf16x8 pf;
                    float zs = 0.f;
                    #pragma unroll
                    for (int uk = 0; uk < 2; ++uk) {
                        const int kGb = k0 + 32 * ks + 16 * uk + 4 * g;
                        const int qG = qb + 16 * uq + r;
                        #pragma unroll
                        for (int i = 0; i < 4; ++i) {
                            const float sv = s[uq][uk][i];
                            float p = 0.03125f * sv * sv;
                            if (diag && (kGb + i > qG)) p = 0.f;
                            zs += p;
                            pf[4 * uk + i] = (__bf16)p;
                        }
                    }
                    if (uq == 0) zacc0 += zs; else zacc1 += zs;
                    #pragma unroll
                    for (int dt = 0; dt < 4; ++dt)
                        oacc[uq][dt] = __builtin_amdgcn_mfma_f32_16x16x32_bf16(
                            vfrag[dt], pf, oacc[uq][dt], 0, 0, 0);
                }
            }
        }
        __syncthreads();
    }
    #pragma unroll
    for (int uq = 0; uq < 2; ++uq) {
        const int q = qb + 16 * uq + r;
        #pragma unroll
        for (int dt = 0; dt < 4; ++dt) {
            float* op = Og + ((size_t)h * SEQN + q) * DVAL + 16 * dt + 4 * g;
            *(f32x4*)op = oacc[uq][dt];
        }
    }
    zacc0 += __shfl_xor(zacc0, 16); zacc0 += __shfl_xor(zacc0, 32);
    zacc1 += __shfl_xor(zacc1, 16); zacc1 += __shfl_xor(zacc1, 32);
    if (lane < 16) {
        float* zp = Og + (size_t)NHEAD * SEQN * DVAL + (size_t)h * SEQN + qb;
        zp[r] = zacc0;
        zp[16 + r] = zacc1;
    }
}

extern "C" void kernel_launch(void* const* d_in, const int* in_sizes, int n_in,
                              void* d_out, int out_size, void* d_ws, size_t ws_size,
                              hipStream_t stream) {
    const float* Q = (const float*)d_in[0];
    const float* K = (const float*)d_in[1];
    const float* V = (const float*)d_in[2];
    float* O = (float*)d_out;

    const size_t G_OFF   = 0;                      // 8*32*80*256 bf16 = 10,485,760 B
    const size_t KBF_OFF = 10485760;               // 8*4096*16 bf16 = 1,048,576 B
    const size_t VTG_OFF = 11534336;               // 8*64*64*64 bf16 = 4,194,304 B
    const size_t NEED    = 15728640;

    if (ws_size >= NEED) {
        char* ws = (char*)d_ws;
        __bf16* G   = (__bf16*)(ws + G_OFF);
        __bf16* Kbf = (__bf16*)(ws + KBF_OFF);
        __bf16* Vtg = (__bf16*)(ws + VTG_OFF);
        p01_state <<<dim3(256), dim3(512), 0, stream>>>(K, V, Kbf, Vtg, G);
        p3m_attend<<<dim3(256), dim3(512), 0, stream>>>(Q, Kbf, Vtg, G, O);
    } else {
        taylor_mono<<<dim3(512), dim3(128), 0, stream>>>(Q, K, V, O);
    }
}

// Round 10
// 30.898 us; speedup vs baseline: 4.6706x; 1.0772x over previous
//
#include <hip/hip_runtime.h>

// Causal quadratic linear attention, chunked-scan formulation.
//   (q.k)^2 = sum_{i,j} q_i q_j k_i k_j   (256 ordered-pair features, f = 16i+j)
// CHUNK=128, NCHUNK=32. THREE launches, all cheap:
// p01   : convert K/V -> bf16 (Kbf, permuted Vtg) + per-chunk state G via
//         operand-swapped MFMA; G stored in FRAGMENT-NATIVE layout so the
//         write is fully coalesced (512B per wave-store).
// p2scan: exclusive prefix over chunks, serial O(NCHUNK) scan, 160 blocks;
//         elementwise -> layout-agnostic. 21MB XCD-pinned traffic.
// p3m   : per (h,c,qh) block (512 x 256): stage Hb[h][c] (40KB) into swizzled
//         LDS (decoding the fragment layout), 4 waves apply state + intra.
// LDS: power-of-2 row strides + XOR swizzle (byte ^= (row&7)<<4).

#define SEQN 4096
#define NHEAD 8
#define DKEY 16
#define DVAL 64
#define CHUNK 128
#define NCHUNK 32
#define ALPHA 0.03125f

typedef float f32x4 __attribute__((ext_vector_type(4)));
typedef __bf16 bf16x4 __attribute__((ext_vector_type(4)));
typedef __bf16 bf16x8 __attribute__((ext_vector_type(8)));
typedef unsigned long long u64;
typedef u64 u64x2 __attribute__((ext_vector_type(2)));

#define SW512(row, colb) (((row) << 9) + ((colb) ^ (((row) & 7) << 4)))
#define SW256(row, colb) (((row) << 8) + ((colb) ^ (((row) & 7) << 4)))

__device__ inline float bf2f(__bf16 x) {
    unsigned short u = __builtin_bit_cast(unsigned short, x);
    unsigned int v = ((unsigned int)u) << 16;
    return __builtin_bit_cast(float, v);
}

// ---------------- Phase 01: convert + per-chunk state ----------------
// grid 256 = (h = bid&7, c = bid>>3), 512 thr (8 waves).
__global__ __launch_bounds__(512, 1)
void p01_state(const float* __restrict__ Kg, const float* __restrict__ Vg,
               __bf16* __restrict__ Kbf, __bf16* __restrict__ Vtg,
               __bf16* __restrict__ G)
{
    __shared__ __align__(128) unsigned char Vt2[80 * 256];   // bf16 [80][128], swz
    __shared__ __align__(128) unsigned char Ktf[16 * 512];   // f32  [16][128], swz
    const int tid = threadIdx.x;
    const int w = tid >> 6;          // wave 0..7
    const int lane = tid & 63;
    const int r = lane & 15, g = lane >> 4;
    const int bid = blockIdx.x;
    const int h = bid & 7, c = bid >> 3;              // c: 0..31
    const int k0 = c * CHUNK;

    // ---- stage K transposed (swz) + write Kbf: key = tid>>2, part = tid&3 ----
    {
        const int key = tid >> 2, part = tid & 3;
        const float* kp = Kg + ((size_t)h * SEQN + k0 + key) * DKEY + 4 * part;
        const f32x4 a = *(const f32x4*)kp;
        #pragma unroll
        for (int j = 0; j < 4; ++j)
            *(float*)(Ktf + SW512(4 * part + j, key * 4)) = a[j];
        bf16x4 o;
        #pragma unroll
        for (int j = 0; j < 4; ++j) o[j] = (__bf16)a[j];
        *(bf16x4*)&Kbf[((size_t)h * SEQN + k0 + key) * DKEY + 4 * part] = o;
    }
    // ---- stage V rows 0..63 (dim el, cols t, swz): seg = tid>>6 (0..7) ----
    {
        const int el = tid & 63;
        const int seg = tid >> 6;
        const float* __restrict__ Vh = Vg + (size_t)h * SEQN * DVAL;
        #pragma unroll
        for (int p = 0; p < 2; ++p) {
            const int tb = 8 * (seg + 8 * p);    // 0..120
            bf16x8 v;
            #pragma unroll
            for (int j = 0; j < 8; ++j)
                v[j] = (__bf16)Vh[(size_t)(k0 + tb + j) * DVAL + el];
            *(bf16x8*)(Vt2 + SW256(el, tb * 2)) = v;
        }
    }
    // ---- rows 64..79: ones (row 64) / zeros, one u64 per thread ----
    {
        const int row = 64 + (tid >> 5);
        const int i = tid & 31;
        const u64 val = (row == 64) ? 0x3F803F803F803F80ULL : 0ULL;
        *(u64*)(Vt2 + SW256(row, 8 * i)) = val;
    }
    __syncthreads();

    // ---- Vtg write-out: permuted V^T (static u64-granular permutation) ----
    #pragma unroll
    for (int uu = 0; uu < 2; ++uu) {
        const int unit = 2 * tid + uu;
        const int m = unit & 3;
        const int hsel = (unit >> 2) & 1;
        const int ktl = (unit >> 3) & 1;
        const int dloc = unit >> 4;
        const u64 t0v = *(const u64*)(Vt2 + SW256(dloc, 128 * ktl + 64 * hsel + 8 * m));
        const u64 t1v = *(const u64*)(Vt2 + SW256(dloc, 128 * ktl + 64 * hsel + 8 * m + 32));
        __bf16* vo = Vtg + ((size_t)((h * 64 + 2 * c + ktl) * 64 + dloc)) * 64 + hsel * 32;
        u64x2 pp; pp[0] = t0v; pp[1] = t1v;
        *(u64x2*)((u64*)vo + 2 * m) = pp;
    }

    // ---- MFMA: G[e][f]; wave w owns f-tiles 2w, 2w+1 (operand-swapped) ----
    f32x4 acc[2][5] = {};
    #pragma unroll
    for (int ks = 0; ks < 4; ++ks) {
        const int t0 = 32 * ks + 8 * g;
        bf16x8 af[5];
        #pragma unroll
        for (int et = 0; et < 5; ++et)
            af[et] = *(const bf16x8*)(Vt2 + SW256(16 * et + r, t0 * 2));
        const f32x4 kra = *(const f32x4*)(Ktf + SW512(r, t0 * 4));
        const f32x4 krb = *(const f32x4*)(Ktf + SW512(r, t0 * 4 + 16));
        #pragma unroll
        for (int fa = 0; fa < 2; ++fa) {
            const int ft = 2 * w + fa;
            const f32x4 kfa = *(const f32x4*)(Ktf + SW512(ft, t0 * 4));
            const f32x4 kfb = *(const f32x4*)(Ktf + SW512(ft, t0 * 4 + 16));
            bf16x8 bfrag;
            #pragma unroll
            for (int j = 0; j < 4; ++j) {
                bfrag[j]     = (__bf16)(kfa[j] * kra[j]);
                bfrag[4 + j] = (__bf16)(kfb[j] * krb[j]);
            }
            #pragma unroll
            for (int et = 0; et < 5; ++et)
                acc[fa][et] = __builtin_amdgcn_mfma_f32_16x16x32_bf16(
                    bfrag, af[et], acc[fa][et], 0, 0, 0);
        }
    }
    // ---- write G in FRAGMENT-NATIVE layout: elem ((wfa*5+et)*64+lane)*4+i ----
    // (e = 16et + (lane&15), f = 16wfa + 4(lane>>4) + i) -- 512B coalesced/wave
    __bf16* Gc = G + (size_t)(h * NCHUNK + c) * 20480;
    #pragma unroll
    for (int fa = 0; fa < 2; ++fa) {
        const int wfa = 2 * w + fa;
        #pragma unroll
        for (int et = 0; et < 5; ++et) {
            bf16x4 o;
            #pragma unroll
            for (int i = 0; i < 4; ++i) o[i] = (__bf16)acc[fa][et][i];
            *(bf16x4*)&Gc[((wfa * 5 + et) * 64 + lane) * 4] = o;
        }
    }
}

// ---------------- Phase 2: exclusive prefix, serial O(NCHUNK) scan ----------------
// grid 160 = (h = bid&7, fb = bid>>3 in 0..19), 256 thr, 4 elems/thread.
// Elementwise -> works directly on the fragment-native layout.
__global__ __launch_bounds__(256)
void p2_scan(const __bf16* __restrict__ G, __bf16* __restrict__ Hb)
{
    const int h = blockIdx.x & 7;
    const int fb = blockIdx.x >> 3;                 // 0..19
    const int fid = fb * 1024 + 4 * threadIdx.x;    // 0..20476
    const __bf16* Gh = G + (size_t)h * NCHUNK * 20480 + fid;
    __bf16* Hh = Hb + (size_t)h * NCHUNK * 20480 + fid;
    f32x4 acc = {};
    #pragma unroll
    for (int cc = 0; cc < NCHUNK; ++cc) {
        bf16x4 o;
        #pragma unroll
        for (int j = 0; j < 4; ++j) o[j] = (__bf16)acc[j];
        *(bf16x4*)&Hh[cc * 20480] = o;
        const bf16x4 v = *(const bf16x4*)&Gh[cc * 20480];
        #pragma unroll
        for (int j = 0; j < 4; ++j) acc[j] += bf2f(v[j]);
    }
}

// ---------------- Phase 3m: LDS-staged state apply + intra-chunk causal ----------------
// grid 512 = (h = bid&7, c, qh), 256 thr (4 waves; wave w: queries qh*64+16w..+15).

#define LOADKV(KT, KF, VF)                                                        \
    {                                                                             \
        const __bf16* Kb_ = Kbf + ((size_t)h * SEQN + (KT) * 64) * DKEY;          \
        const __bf16* Vb_ = Vtg + (size_t)((h * 64 + (KT)) * 64) * 64;            \
        _Pragma("unroll")                                                         \
        for (int ks_ = 0; ks_ < 2; ++ks_) {                                       \
            _Pragma("unroll")                                                     \
            for (int uk_ = 0; uk_ < 2; ++uk_) {                                   \
                bf16x8 f_ = {};                                                   \
                if (g < 2)                                                        \
                    f_ = *(const bf16x8*)&Kb_[(32 * ks_ + 16 * uk_ + r) * DKEY + 8 * g]; \
                KF[ks_][uk_] = f_;                                                \
            }                                                                     \
            _Pragma("unroll")                                                     \
            for (int dt_ = 0; dt_ < 4; ++dt_)                                     \
                VF[ks_][dt_] = *(const bf16x8*)&Vb_[(size_t)(16 * dt_ + r) * 64 + 32 * ks_ + 8 * g]; \
        }                                                                         \
    }

__global__ __launch_bounds__(256, 2)
void p3m_attend(const float* __restrict__ Qg, const __bf16* __restrict__ Kbf,
                const __bf16* __restrict__ Vtg, const __bf16* __restrict__ Hb,
                float* __restrict__ Og)
{
    __shared__ __align__(128) unsigned char Hlds[80 * 512];   // bf16 [80][256], swz
    const int tid = threadIdx.x;
    const int lane = tid & 63;
    const int r = lane & 15, g = lane >> 4;
    const int w = tid >> 6;          // wave 0..3
    const int bid = blockIdx.x;
    const int h = bid & 7;
    const int x = bid >> 3;          // 0..63
    const int c = x >> 1;            // 0..31
    const int qh = x & 1;
    const int qb = c * CHUNK + qh * 64 + 16 * w;

    // ---- Q row (fp32) ----
    float qr[16];
    {
        const float* qp = Qg + ((size_t)h * SEQN + qb + r) * DKEY;
        #pragma unroll
        for (int m = 0; m < 4; ++m) {
            const f32x4 v = *(const f32x4*)(qp + 4 * m);
            qr[4 * m + 0] = v[0]; qr[4 * m + 1] = v[1];
            qr[4 * m + 2] = v[2]; qr[4 * m + 3] = v[3];
        }
    }
    float qsel[8];
    #pragma unroll
    for (int j = 0; j < 8; ++j) qsel[j] = (g & 1) ? qr[8 + j] : qr[j];
    bf16x8 qfrag = {};
    if (g < 2) {
        #pragma unroll
        for (int j = 0; j < 8; ++j) qfrag[j] = (__bf16)qsel[j];
    }

    // ---- prefetch intra tile(s); stage Hb[h][c] into LDS (decode frag layout) ----
    bf16x8 kf0[2][2], vf0[2][4], kf1[2][2], vf1[2][4];
    LOADKV(2 * c, kf0, vf0);

    if (c > 0) {
        const __bf16* Hbc = Hb + (size_t)(h * NCHUNK + c) * 20480;
        #pragma unroll
        for (int k2 = 0; k2 < 10; ++k2) {
            const int U = tid + 256 * k2;            // 16B unit, 2560 total
            const int wfa = U / 160;                 // 0..15
            const int rem = U - wfa * 160;
            const int et = rem >> 5;                 // 0..4
            const int lp = rem & 31;                 // lane pair
            const int L0 = 2 * lp, L1 = L0 + 1;
            const int e0 = 16 * et + (L0 & 15), f0 = 16 * wfa + 4 * (L0 >> 4);
            const int e1 = 16 * et + (L1 & 15), f1 = 16 * wfa + 4 * (L1 >> 4);
            const u64x2 v = *(const u64x2*)&Hbc[U * 8];
            *(u64*)(Hlds + SW512(e0, 2 * f0)) = v[0];
            *(u64*)(Hlds + SW512(e1, 2 * f1)) = v[1];
        }
    }
    if (qh == 1) LOADKV(2 * c + 1, kf1, vf1);

    f32x4 oacc[4] = {};
    f32x4 zacc4 = {};
    float zin = 0.f;

    // ---- state apply from LDS: O += Psi(q) x H_{<c} ----
    if (c > 0) {
        __syncthreads();
        #pragma unroll
        for (int ks = 0; ks < 8; ++ks) {
            const int t0 = 32 * ks + 8 * g;
            bf16x8 af[4];
            #pragma unroll
            for (int dt = 0; dt < 4; ++dt)
                af[dt] = *(const bf16x8*)(Hlds + SW512(16 * dt + r, t0 * 2));
            const bf16x8 afz = *(const bf16x8*)(Hlds + SW512(64 + r, t0 * 2));
            const float qi = ALPHA * ((g & 2) ? qr[2 * ks + 1] : qr[2 * ks]);
            bf16x8 pf;
            #pragma unroll
            for (int j = 0; j < 8; ++j) pf[j] = (__bf16)(qi * qsel[j]);
            #pragma unroll
            for (int dt = 0; dt < 4; ++dt)
                oacc[dt] = __builtin_amdgcn_mfma_f32_16x16x32_bf16(af[dt], pf, oacc[dt], 0, 0, 0);
            zacc4 = __builtin_amdgcn_mfma_f32_16x16x32_bf16(afz, pf, zacc4, 0, 0, 0);
        }
    }

    // ---- intra-chunk causal tiles ----
    const int qG = qb + r;
    const int qlocmax = qh * 64 + 16 * w + 15;   // wave's max local query
    #pragma unroll
    for (int tl = 0; tl < 2; ++tl) {
        if (tl <= qh) {
            const bool diag = (tl == qh);
            const int k0g = (2 * c + tl) * 64;
            #pragma unroll
            for (int ks = 0; ks < 2; ++ks) {
                if (64 * tl + 32 * ks <= qlocmax) {   // wave-uniform
                    const f32x4 zero4 = {};
                    f32x4 s[2];
                    #pragma unroll
                    for (int uk = 0; uk < 2; ++uk)
                        s[uk] = __builtin_amdgcn_mfma_f32_16x16x32_bf16(
                            (tl == 0) ? kf0[ks][uk] : kf1[ks][uk], qfrag, zero4, 0, 0, 0);
                    bf16x8 pf;
                    float zs = 0.f;
                    #pragma unroll
                    for (int uk = 0; uk < 2; ++uk) {
                        const int kGb = k0g + 32 * ks + 16 * uk + 4 * g;
                        #pragma unroll
                        for (int i = 0; i < 4; ++i) {
                            const float sv = s[uk][i];
                            float p = ALPHA * sv * sv;
                            if (diag && (kGb + i > qG)) p = 0.f;
                            zs += p;
                            pf[4 * uk + i] = (__bf16)p;
                        }
                    }
                    zin += zs;
                    #pragma unroll
                    for (int dt = 0; dt < 4; ++dt)
                        oacc[dt] = __builtin_amdgcn_mfma_f32_16x16x32_bf16(
                            (tl == 0) ? vf0[ks][dt] : vf1[ks][dt], pf, oacc[dt], 0, 0, 0);
                }
            }
        }
    }

    // ---- stores ----
    const int q = qb + r;
    #pragma unroll
    for (int dt = 0; dt < 4; ++dt) {
        float* op = Og + ((size_t)h * SEQN + q) * DVAL + 16 * dt + 4 * g;
        *(f32x4*)op = oacc[dt];
    }
    zin += __shfl_xor(zin, 16); zin += __shfl_xor(zin, 32);
    if (lane < 16) {   // g==0: zacc4[0] holds the e=64 (ones) row for query r
        float* zp = Og + (size_t)NHEAD * SEQN * DVAL + (size_t)h * SEQN + qb;
        zp[r] = zin + zacc4[0];
    }
}

// ---------------- Fallback (monolithic) if workspace too small ----------------
__global__ __launch_bounds__(128, 2)
void taylor_mono(const float* __restrict__ Qg, const float* __restrict__ Kg,
                 const float* __restrict__ Vg, float* __restrict__ Og)
{
    __shared__ __align__(16) __bf16 Kl[64 * 32];
    __shared__ __align__(16) __bf16 Vt[64 * 72];
    typedef __bf16 bf16x2 __attribute__((ext_vector_type(2)));
    const int tid = threadIdx.x;
    const int wv = tid >> 6;
    const int lane = tid & 63;
    const int r = lane & 15, g = lane >> 4;
    const int bid = blockIdx.x;
    const int h = bid & 7;
    const int tt = bid >> 3;
    const int qt = (tt & 1) ? (tt >> 1) : (63 - (tt >> 1));
    const int qb = qt * 64 + wv * 32;
    const float* __restrict__ Qh = Qg + (size_t)h * SEQN * DKEY;
    const float* __restrict__ Kh = Kg + (size_t)h * SEQN * DKEY;
    const float* __restrict__ Vh = Vg + (size_t)h * SEQN * DVAL;
    for (int row = tid; row < 64; row += 128) {
        bf16x8 z = {};
        *(bf16x8*)&Kl[row * 32 + 16] = z;
        *(bf16x8*)&Kl[row * 32 + 24] = z;
    }
    bf16x8 qfrag[2];
    #pragma unroll
    for (int uq = 0; uq < 2; ++uq) {
        bf16x8 f = {};
        if (g < 2) {
            const float* qp = Qh + (size_t)(qb + 16 * uq + r) * DKEY + 8 * g;
            const f32x4 a = *(const f32x4*)qp;
            const f32x4 b = *(const f32x4*)(qp + 4);
            #pragma unroll
            for (int j = 0; j < 4; ++j) { f[j] = (__bf16)a[j]; f[4 + j] = (__bf16)b[j]; }
        }
        qfrag[uq] = f;
    }
    f32x4 oacc[2][4] = {};
    float zacc0 = 0.f, zacc1 = 0.f;
    const int nkt = qt + 1;
    for (int kt = 0; kt < nkt; ++kt) {
        const int k0 = kt * 64;
        {
            const int key = tid >> 1, half = tid & 1;
            const float* kp = Kh + (size_t)(k0 + key) * DKEY + 8 * half;
            const f32x4 a = *(const f32x4*)kp;
            const f32x4 b = *(const f32x4*)(kp + 4);
            bf16x8 kb;
            #pragma unroll
            for (int j = 0; j < 4; ++j) { kb[j] = (__bf16)a[j]; kb[4 + j] = (__bf16)b[j]; }
            *(bf16x8*)&Kl[key * 32 + 8 * half] = kb;
        }
        {
            const int d = tid & 63;
            const int kp2 = (tid >> 6) * 2;
            #pragma unroll
            for (int i = 0; i < 16; ++i) {
                const int kk = i * 4 + kp2;
                const float a0 = Vh[(size_t)(k0 + kk) * DVAL + d];
                const float a1 = Vh[(size_t)(k0 + kk + 1) * DVAL + d];
                const int w32 = kk & 31;
                const int col = (kk & 32) + ((w32 >> 2) & 3) * 8 + ((w32 >> 4) << 2) + (kk & 3);
                bf16x2 p; p[0] = (__bf16)a0; p[1] = (__bf16)a1;
                *(bf16x2*)&Vt[d * 72 + col] = p;
            }
        }
        __syncthreads();
        const bool diag = (kt + 1 == nkt);
        #pragma unroll
        for (int ks = 0; ks < 2; ++ks) {
            if (k0 + 32 * ks < qb + 32) {
                bf16x8 vfrag[4];
                #pragma unroll
                for (int dt = 0; dt < 4; ++dt)
                    vfrag[dt] = *(const bf16x8*)&Vt[(16 * dt + r) * 72 + 32 * ks + 8 * g];
                bf16x8 kfr[2];
                #pragma unroll
                for (int uk = 0; uk < 2; ++uk)
                    kfr[uk] = *(const bf16x8*)&Kl[(32 * ks + 16 * uk + r) * 32 + 8 * g];
                const f32x4 zero4 = {};
                f32x4 s[2][2];
                #pragma unroll
                for (int uq = 0; uq < 2; ++uq)
                    #pragma unroll
                    for (int uk = 0; uk < 2; ++uk)
                        s[uq][uk] = __builtin_amdgcn_mfma_f32_16x16x32_bf16(
                            kfr[uk], qfrag[uq], zero4, 0, 0, 0);
                #pragma unroll
                for (int uq = 0; uq < 2; ++uq) {
                    bf16x8 pf;
                    float zs = 0.f;
                    #pragma unroll
                    for (int uk = 0; uk < 2; ++uk) {
                        const int kGb = k0 + 32 * ks + 16 * uk + 4 * g;
                        const int qG = qb + 16 * uq + r;
                        #pragma unroll
                        for (int i = 0; i < 4; ++i) {
                            const float sv = s[uq][uk][i];
                            float p = 0.03125f * sv * sv;
                            if (diag && (kGb + i > qG)) p = 0.f;
                            zs += p;
                            pf[4 * uk + i] = (__bf16)p;
                        }
                    }
                    if (uq == 0) zacc0 += zs; else zacc1 += zs;
                    #pragma unroll
                    for (int dt = 0; dt < 4; ++dt)
                        oacc[uq][dt] = __builtin_amdgcn_mfma_f32_16x16x32_bf16(
                            vfrag[dt], pf, oacc[uq][dt], 0, 0, 0);
                }
            }
        }
        __syncthreads();
    }
    #pragma unroll
    for (int uq = 0; uq < 2; ++uq) {
        const int q = qb + 16 * uq + r;
        #pragma unroll
        for (int dt = 0; dt < 4; ++dt) {
            float* op = Og + ((size_t)h * SEQN + q) * DVAL + 16 * dt + 4 * g;
            *(f32x4*)op = oacc[uq][dt];
        }
    }
    zacc0 += __shfl_xor(zacc0, 16); zacc0 += __shfl_xor(zacc0, 32);
    zacc1 += __shfl_xor(zacc1, 16); zacc1 += __shfl_xor(zacc1, 32);
    if (lane < 16) {
        float* zp = Og + (size_t)NHEAD * SEQN * DVAL + (size_t)h * SEQN + qb;
        zp[r] = zacc0;
        zp[16 + r] = zacc1;
    }
}

extern "C" void kernel_launch(void* const* d_in, const int* in_sizes, int n_in,
                              void* d_out, int out_size, void* d_ws, size_t ws_size,
                              hipStream_t stream) {
    const float* Q = (const float*)d_in[0];
    const float* K = (const float*)d_in[1];
    const float* V = (const float*)d_in[2];
    float* O = (float*)d_out;

    const size_t G_OFF   = 0;                      // 8*32*20480 bf16 = 10,485,760 B
    const size_t HB_OFF  = 10485760;               // same size
    const size_t KBF_OFF = 20971520;               // 8*4096*16 bf16 = 1,048,576 B
    const size_t VTG_OFF = 22020096;               // 8*64*64*64 bf16 = 4,194,304 B
    const size_t NEED    = 26214400;

    if (ws_size >= NEED) {
        char* ws = (char*)d_ws;
        __bf16* G   = (__bf16*)(ws + G_OFF);
        __bf16* Hb  = (__bf16*)(ws + HB_OFF);
        __bf16* Kbf = (__bf16*)(ws + KBF_OFF);
        __bf16* Vtg = (__bf16*)(ws + VTG_OFF);
        p01_state <<<dim3(256), dim3(512), 0, stream>>>(K, V, Kbf, Vtg, G);
        p2_scan   <<<dim3(160), dim3(256), 0, stream>>>(G, Hb);
        p3m_attend<<<dim3(512), dim3(256), 0, stream>>>(Q, Kbf, Vtg, Hb, O);
    } else {
        taylor_mono<<<dim3(512), dim3(128), 0, stream>>>(Q, K, V, O);
    }
}

// Round 11
// 28.399 us; speedup vs baseline: 5.0816x; 1.0880x over previous
//
#include <hip/hip_runtime.h>

// Causal quadratic linear attention, chunked-scan formulation.
//   (q.k)^2 = sum_{i,j} q_i q_j k_i k_j   (256 ordered-pair features, f = 16i+j)
// CHUNK=128, NCHUNK=32. THREE launches:
// p01   : stage K (Ktf f32 + Kl bf16) and V (Vt2) in LDS; per-chunk state G
//         via operand-swapped MFMA (frag-native coalesced write); THEN the
//         same block's 8 waves compute the intra-chunk causal part from the
//         staged LDS tiles and store O/Z (partial: intra only).
// p2scan: exclusive prefix over chunks, serial O(NCHUNK) scan, elementwise
//         on the fragment-native layout. 160 blocks, XCD-pinned.
// p3s   : state-apply only: per (h,c,qh) block (512 x 256thr, c=0 exits),
//         stage Hb[h][c] (40KB) into swizzled LDS (frag decode), 45 MFMAs,
//         O += state (RMW of p01's partial), Z += state.
// LDS: power-of-2 row strides + XOR swizzle (byte ^= (row&7)<<4).

#define SEQN 4096
#define NHEAD 8
#define DKEY 16
#define DVAL 64
#define CHUNK 128
#define NCHUNK 32
#define ALPHA 0.03125f

typedef float f32x4 __attribute__((ext_vector_type(4)));
typedef __bf16 bf16x4 __attribute__((ext_vector_type(4)));
typedef __bf16 bf16x8 __attribute__((ext_vector_type(8)));
typedef unsigned long long u64;
typedef u64 u64x2 __attribute__((ext_vector_type(2)));

#define SW512(row, colb) (((row) << 9) + ((colb) ^ (((row) & 7) << 4)))
#define SW256(row, colb) (((row) << 8) + ((colb) ^ (((row) & 7) << 4)))

__device__ inline float bf2f(__bf16 x) {
    unsigned short u = __builtin_bit_cast(unsigned short, x);
    unsigned int v = ((unsigned int)u) << 16;
    return __builtin_bit_cast(float, v);
}

// ---------------- Phase 01: stage + chunk state + intra attention ----------------
// grid 256 = (h = bid&7, c = bid>>3), 512 thr (8 waves; wave w: queries 16w..+15).
__global__ __launch_bounds__(512, 1)
void p01_state(const float* __restrict__ Kg, const float* __restrict__ Vg,
               const float* __restrict__ Qg, __bf16* __restrict__ G,
               float* __restrict__ Og)
{
    __shared__ __align__(128) unsigned char Vt2[80 * 256];   // bf16 [80][128], swz (20KB)
    __shared__ __align__(128) unsigned char Ktf[16 * 512];   // f32  [16][128], swz (8KB)
    __shared__ __align__(128) unsigned char Kl[128 * 32];    // bf16 [128][16], swz (4KB)
    const int tid = threadIdx.x;
    const int w = tid >> 6;          // wave 0..7
    const int lane = tid & 63;
    const int r = lane & 15, g = lane >> 4;
    const int bid = blockIdx.x;
    const int h = bid & 7, c = bid >> 3;              // c: 0..31
    const int k0 = c * CHUNK;
    const int qb = k0 + 16 * w;

    // ---- Q row load (issued early, in flight during staging) ----
    float qr[16];
    {
        const float* qp = Qg + ((size_t)h * SEQN + qb + r) * DKEY;
        #pragma unroll
        for (int m = 0; m < 4; ++m) {
            const f32x4 v = *(const f32x4*)(qp + 4 * m);
            qr[4 * m + 0] = v[0]; qr[4 * m + 1] = v[1];
            qr[4 * m + 2] = v[2]; qr[4 * m + 3] = v[3];
        }
    }

    // ---- stage K: Ktf (f32 transposed, swz) + Kl (bf16 row-major, swz) ----
    {
        const int key = tid >> 2, part = tid & 3;
        const float* kp = Kg + ((size_t)h * SEQN + k0 + key) * DKEY + 4 * part;
        const f32x4 a = *(const f32x4*)kp;
        #pragma unroll
        for (int j = 0; j < 4; ++j)
            *(float*)(Ktf + SW512(4 * part + j, key * 4)) = a[j];
        bf16x4 o;
        #pragma unroll
        for (int j = 0; j < 4; ++j) o[j] = (__bf16)a[j];
        *(bf16x4*)(Kl + key * 32 + ((8 * part) ^ ((key & 1) << 4))) = o;
    }
    // ---- stage V rows 0..63 (dim el, cols t, swz) ----
    {
        const int el = tid & 63;
        const int seg = tid >> 6;
        const float* __restrict__ Vh = Vg + (size_t)h * SEQN * DVAL;
        #pragma unroll
        for (int p = 0; p < 2; ++p) {
            const int tb = 8 * (seg + 8 * p);    // 0..120
            bf16x8 v;
            #pragma unroll
            for (int j = 0; j < 8; ++j)
                v[j] = (__bf16)Vh[(size_t)(k0 + tb + j) * DVAL + el];
            *(bf16x8*)(Vt2 + SW256(el, tb * 2)) = v;
        }
    }
    // ---- rows 64..79: ones (row 64) / zeros ----
    {
        const int row = 64 + (tid >> 5);
        const int i = tid & 31;
        const u64 val = (row == 64) ? 0x3F803F803F803F80ULL : 0ULL;
        *(u64*)(Vt2 + SW256(row, 8 * i)) = val;
    }
    __syncthreads();

    // ---- MFMA: G[e][f]; wave w owns f-tiles 2w, 2w+1 (operand-swapped) ----
    {
        f32x4 acc[2][5] = {};
        #pragma unroll
        for (int ks = 0; ks < 4; ++ks) {
            const int t0 = 32 * ks + 8 * g;
            bf16x8 af[5];
            #pragma unroll
            for (int et = 0; et < 5; ++et)
                af[et] = *(const bf16x8*)(Vt2 + SW256(16 * et + r, t0 * 2));
            const f32x4 kra = *(const f32x4*)(Ktf + SW512(r, t0 * 4));
            const f32x4 krb = *(const f32x4*)(Ktf + SW512(r, t0 * 4 + 16));
            #pragma unroll
            for (int fa = 0; fa < 2; ++fa) {
                const int ft = 2 * w + fa;
                const f32x4 kfa = *(const f32x4*)(Ktf + SW512(ft, t0 * 4));
                const f32x4 kfb = *(const f32x4*)(Ktf + SW512(ft, t0 * 4 + 16));
                bf16x8 bfrag;
                #pragma unroll
                for (int j = 0; j < 4; ++j) {
                    bfrag[j]     = (__bf16)(kfa[j] * kra[j]);
                    bfrag[4 + j] = (__bf16)(kfb[j] * krb[j]);
                }
                #pragma unroll
                for (int et = 0; et < 5; ++et)
                    acc[fa][et] = __builtin_amdgcn_mfma_f32_16x16x32_bf16(
                        bfrag, af[et], acc[fa][et], 0, 0, 0);
            }
        }
        // fragment-native coalesced write: elem ((wfa*5+et)*64+lane)*4+i
        // (e = 16et + (lane&15), f = 16wfa + 4(lane>>4) + i)
        __bf16* Gc = G + (size_t)(h * NCHUNK + c) * 20480;
        #pragma unroll
        for (int fa = 0; fa < 2; ++fa) {
            const int wfa = 2 * w + fa;
            #pragma unroll
            for (int et = 0; et < 5; ++et) {
                bf16x4 o;
                #pragma unroll
                for (int i = 0; i < 4; ++i) o[i] = (__bf16)acc[fa][et][i];
                *(bf16x4*)&Gc[((wfa * 5 + et) * 64 + lane) * 4] = o;
            }
        }
    }

    // ---- intra-chunk causal attention from LDS (Kl + Vt2 read-time permute) ----
    float qsel[8];
    #pragma unroll
    for (int j = 0; j < 8; ++j) qsel[j] = (g & 1) ? qr[8 + j] : qr[j];
    bf16x8 qfrag = {};
    if (g < 2) {
        #pragma unroll
        for (int j = 0; j < 8; ++j) qfrag[j] = (__bf16)qsel[j];
    }

    f32x4 oacc[4] = {};
    float zin = 0.f;
    const int qG = qb + r;
    const int smax = w >> 1;    // include 32-key subtiles sidx <= smax
    #pragma unroll
    for (int tl = 0; tl < 2; ++tl) {
        #pragma unroll
        for (int ks = 0; ks < 2; ++ks) {
            const int sidx = 2 * tl + ks;
            if (sidx <= smax) {
                const bool diag = (sidx == smax);
                bf16x8 kf[2];
                #pragma unroll
                for (int uk = 0; uk < 2; ++uk) {
                    bf16x8 f = {};
                    if (g < 2) {
                        const int key = 64 * tl + 32 * ks + 16 * uk + r;
                        f = *(const bf16x8*)(Kl + key * 32 + ((16 * g) ^ ((key & 1) << 4)));
                    }
                    kf[uk] = f;
                }
                const f32x4 zero4 = {};
                f32x4 s[2];
                #pragma unroll
                for (int uk = 0; uk < 2; ++uk)
                    s[uk] = __builtin_amdgcn_mfma_f32_16x16x32_bf16(kf[uk], qfrag, zero4, 0, 0, 0);

                bf16x8 pf;
                float zs = 0.f;
                const int k0g = k0 + 64 * tl + 32 * ks;
                #pragma unroll
                for (int uk = 0; uk < 2; ++uk) {
                    const int kGb = k0g + 16 * uk + 4 * g;
                    #pragma unroll
                    for (int i = 0; i < 4; ++i) {
                        const float sv = s[uk][i];
                        float p = ALPHA * sv * sv;
                        if (diag && (kGb + i > qG)) p = 0.f;
                        zs += p;
                        pf[4 * uk + i] = (__bf16)p;
                    }
                }
                zin += zs;
                #pragma unroll
                for (int dt = 0; dt < 4; ++dt) {
                    const int base = 128 * tl + 64 * ks + 8 * g;
                    u64x2 both;
                    both[0] = *(const u64*)(Vt2 + SW256(16 * dt + r, base));
                    both[1] = *(const u64*)(Vt2 + SW256(16 * dt + r, base + 32));
                    const bf16x8 vf = __builtin_bit_cast(bf16x8, both);
                    oacc[dt] = __builtin_amdgcn_mfma_f32_16x16x32_bf16(vf, pf, oacc[dt], 0, 0, 0);
                }
            }
        }
    }

    // ---- store intra-partial O and Z ----
    const int q = qb + r;
    #pragma unroll
    for (int dt = 0; dt < 4; ++dt) {
        float* op = Og + ((size_t)h * SEQN + q) * DVAL + 16 * dt + 4 * g;
        *(f32x4*)op = oacc[dt];
    }
    zin += __shfl_xor(zin, 16); zin += __shfl_xor(zin, 32);
    if (lane < 16) {
        float* zp = Og + (size_t)NHEAD * SEQN * DVAL + (size_t)h * SEQN + qb;
        zp[r] = zin;
    }
}

// ---------------- Phase 2: exclusive prefix, serial O(NCHUNK) scan ----------------
// grid 160 = (h = bid&7, fb = bid>>3 in 0..19), 256 thr, 4 elems/thread.
__global__ __launch_bounds__(256)
void p2_scan(const __bf16* __restrict__ G, __bf16* __restrict__ Hb)
{
    const int h = blockIdx.x & 7;
    const int fb = blockIdx.x >> 3;                 // 0..19
    const int fid = fb * 1024 + 4 * threadIdx.x;    // 0..20476
    const __bf16* Gh = G + (size_t)h * NCHUNK * 20480 + fid;
    __bf16* Hh = Hb + (size_t)h * NCHUNK * 20480 + fid;
    f32x4 acc = {};
    #pragma unroll
    for (int cc = 0; cc < NCHUNK; ++cc) {
        bf16x4 o;
        #pragma unroll
        for (int j = 0; j < 4; ++j) o[j] = (__bf16)acc[j];
        *(bf16x4*)&Hh[cc * 20480] = o;
        const bf16x4 v = *(const bf16x4*)&Gh[cc * 20480];
        #pragma unroll
        for (int j = 0; j < 4; ++j) acc[j] += bf2f(v[j]);
    }
}

// ---------------- Phase 3s: state apply only (O/Z read-modify-write) ----------------
// grid 512 = (h = bid&7, c, qh), 256 thr (4 waves; wave w: queries qh*64+16w..+15).
__global__ __launch_bounds__(256, 2)
void p3s_apply(const float* __restrict__ Qg, const __bf16* __restrict__ Hb,
               float* __restrict__ Og)
{
    __shared__ __align__(128) unsigned char Hlds[80 * 512];   // bf16 [80][256], swz
    const int tid = threadIdx.x;
    const int lane = tid & 63;
    const int r = lane & 15, g = lane >> 4;
    const int w = tid >> 6;          // wave 0..3
    const int bid = blockIdx.x;
    const int h = bid & 7;
    const int x = bid >> 3;          // 0..63
    const int c = x >> 1;            // 0..31
    const int qh = x & 1;
    if (c == 0) return;              // no state for chunk 0 (uniform exit)
    const int qb = c * CHUNK + qh * 64 + 16 * w;
    const int q = qb + r;

    // ---- prefetch Q row, O-partial, Z-partial (in flight during stage) ----
    float qr[16];
    {
        const float* qp = Qg + ((size_t)h * SEQN + q) * DKEY;
        #pragma unroll
        for (int m = 0; m < 4; ++m) {
            const f32x4 v = *(const f32x4*)(qp + 4 * m);
            qr[4 * m + 0] = v[0]; qr[4 * m + 1] = v[1];
            qr[4 * m + 2] = v[2]; qr[4 * m + 3] = v[3];
        }
    }
    f32x4 oprev[4];
    #pragma unroll
    for (int dt = 0; dt < 4; ++dt)
        oprev[dt] = *(const f32x4*)(Og + ((size_t)h * SEQN + q) * DVAL + 16 * dt + 4 * g);
    float* zp = Og + (size_t)NHEAD * SEQN * DVAL + (size_t)h * SEQN + qb;
    const float zprev = zp[r];

    // ---- stage Hb[h][c] into LDS (decode fragment-native layout, swz) ----
    {
        const __bf16* Hbc = Hb + (size_t)(h * NCHUNK + c) * 20480;
        #pragma unroll
        for (int k2 = 0; k2 < 10; ++k2) {
            const int U = tid + 256 * k2;            // 16B unit, 2560 total
            const int wfa = U / 160;                 // 0..15
            const int rem = U - wfa * 160;
            const int et = rem >> 5;                 // 0..4
            const int lp = rem & 31;                 // lane pair
            const int L0 = 2 * lp, L1 = L0 + 1;
            const int e0 = 16 * et + (L0 & 15), f0 = 16 * wfa + 4 * (L0 >> 4);
            const int e1 = 16 * et + (L1 & 15), f1 = 16 * wfa + 4 * (L1 >> 4);
            const u64x2 v = *(const u64x2*)&Hbc[U * 8];
            *(u64*)(Hlds + SW512(e0, 2 * f0)) = v[0];
            *(u64*)(Hlds + SW512(e1, 2 * f1)) = v[1];
        }
    }
    __syncthreads();

    // ---- state apply: O += Psi(q) x H_{<c} ----
    float qsel[8];
    #pragma unroll
    for (int j = 0; j < 8; ++j) qsel[j] = (g & 1) ? qr[8 + j] : qr[j];
    f32x4 oacc[4] = {};
    f32x4 zacc4 = {};
    #pragma unroll
    for (int ks = 0; ks < 8; ++ks) {
        const int t0 = 32 * ks + 8 * g;
        bf16x8 af[4];
        #pragma unroll
        for (int dt = 0; dt < 4; ++dt)
            af[dt] = *(const bf16x8*)(Hlds + SW512(16 * dt + r, t0 * 2));
        const bf16x8 afz = *(const bf16x8*)(Hlds + SW512(64 + r, t0 * 2));
        const float qi = ALPHA * ((g & 2) ? qr[2 * ks + 1] : qr[2 * ks]);
        bf16x8 pf;
        #pragma unroll
        for (int j = 0; j < 8; ++j) pf[j] = (__bf16)(qi * qsel[j]);
        #pragma unroll
        for (int dt = 0; dt < 4; ++dt)
            oacc[dt] = __builtin_amdgcn_mfma_f32_16x16x32_bf16(af[dt], pf, oacc[dt], 0, 0, 0);
        zacc4 = __builtin_amdgcn_mfma_f32_16x16x32_bf16(afz, pf, zacc4, 0, 0, 0);
    }

    // ---- final stores: O = intra + state ----
    #pragma unroll
    for (int dt = 0; dt < 4; ++dt) {
        float* op = Og + ((size_t)h * SEQN + q) * DVAL + 16 * dt + 4 * g;
        f32x4 o = oprev[dt];
        #pragma unroll
        for (int i = 0; i < 4; ++i) o[i] += oacc[dt][i];
        *(f32x4*)op = o;
    }
    if (lane < 16)
        zp[r] = zprev + zacc4[0];
}

// ---------------- Fallback (monolithic) if workspace too small ----------------
__global__ __launch_bounds__(128, 2)
void taylor_mono(const float* __restrict__ Qg, const float* __restrict__ Kg,
                 const float* __restrict__ Vg, float* __restrict__ Og)
{
    __shared__ __align__(16) __bf16 Kl[64 * 32];
    __shared__ __align__(16) __bf16 Vt[64 * 72];
    typedef __bf16 bf16x2 __attribute__((ext_vector_type(2)));
    const int tid = threadIdx.x;
    const int wv = tid >> 6;
    const int lane = tid & 63;
    const int r = lane & 15, g = lane >> 4;
    const int bid = blockIdx.x;
    const int h = bid & 7;
    const int tt = bid >> 3;
    const int qt = (tt & 1) ? (tt >> 1) : (63 - (tt >> 1));
    const int qb = qt * 64 + wv * 32;
    const float* __restrict__ Qh = Qg + (size_t)h * SEQN * DKEY;
    const float* __restrict__ Kh = Kg + (size_t)h * SEQN * DKEY;
    const float* __restrict__ Vh = Vg + (size_t)h * SEQN * DVAL;
    for (int row = tid; row < 64; row += 128) {
        bf16x8 z = {};
        *(bf16x8*)&Kl[row * 32 + 16] = z;
        *(bf16x8*)&Kl[row * 32 + 24] = z;
    }
    bf16x8 qfrag[2];
    #pragma unroll
    for (int uq = 0; uq < 2; ++uq) {
        bf16x8 f = {};
        if (g < 2) {
            const float* qp = Qh + (size_t)(qb + 16 * uq + r) * DKEY + 8 * g;
            const f32x4 a = *(const f32x4*)qp;
            const f32x4 b = *(const f32x4*)(qp + 4);
            #pragma unroll
            for (int j = 0; j < 4; ++j) { f[j] = (__bf16)a[j]; f[4 + j] = (__bf16)b[j]; }
        }
        qfrag[uq] = f;
    }
    f32x4 oacc[2][4] = {};
    float zacc0 = 0.f, zacc1 = 0.f;
    const int nkt = qt + 1;
    for (int kt = 0; kt < nkt; ++kt) {
        const int k0 = kt * 64;
        {
            const int key = tid >> 1, half = tid & 1;
            const float* kp = Kh + (size_t)(k0 + key) * DKEY + 8 * half;
            const f32x4 a = *(const f32x4*)kp;
            const f32x4 b = *(const f32x4*)(kp + 4);
            bf16x8 kb;
            #pragma unroll
            for (int j = 0; j < 4; ++j) { kb[j] = (__bf16)a[j]; kb[4 + j] = (__bf16)b[j]; }
            *(bf16x8*)&Kl[key * 32 + 8 * half] = kb;
        }
        {
            const int d = tid & 63;
            const int kp2 = (tid >> 6) * 2;
            #pragma unroll
            for (int i = 0; i < 16; ++i) {
                const int kk = i * 4 + kp2;
                const float a0 = Vh[(size_t)(k0 + kk) * DVAL + d];
                const float a1 = Vh[(size_t)(k0 + kk + 1) * DVAL + d];
                const int w32 = kk & 31;
                const int col = (kk & 32) + ((w32 >> 2) & 3) * 8 + ((w32 >> 4) << 2) + (kk & 3);
                bf16x2 p; p[0] = (__bf16)a0; p[1] = (__bf16)a1;
                *(bf16x2*)&Vt[d * 72 + col] = p;
            }
        }
        __syncthreads();
        const bool diag = (kt + 1 == nkt);
        #pragma unroll
        for (int ks = 0; ks < 2; ++ks) {
            if (k0 + 32 * ks < qb + 32) {
                bf16x8 vfrag[4];
                #pragma unroll
                for (int dt = 0; dt < 4; ++dt)
                    vfrag[dt] = *(const bf16x8*)&Vt[(16 * dt + r) * 72 + 32 * ks + 8 * g];
                bf16x8 kfr[2];
                #pragma unroll
                for (int uk = 0; uk < 2; ++uk)
                    kfr[uk] = *(const bf16x8*)&Kl[(32 * ks + 16 * uk + r) * 32 + 8 * g];
                const f32x4 zero4 = {};
                f32x4 s[2][2];
                #pragma unroll
                for (int uq = 0; uq < 2; ++uq)
                    #pragma unroll
                    for (int uk = 0; uk < 2; ++uk)
                        s[uq][uk] = __builtin_amdgcn_mfma_f32_16x16x32_bf16(
                            kfr[uk], qfrag[uq], zero4, 0, 0, 0);
                #pragma unroll
                for (int uq = 0; uq < 2; ++uq) {
                    bf16x8 pf;
                    float zs = 0.f;
                    #pragma unroll
                    for (int uk = 0; uk < 2; ++uk) {
                        const int kGb = k0 + 32 * ks + 16 * uk + 4 * g;
                        const int qG = qb + 16 * uq + r;
                        #pragma unroll
                        for (int i = 0; i < 4; ++i) {
                            const float sv = s[uq][uk][i];
                            float p = 0.03125f * sv * sv;
                            if (diag && (kGb + i > qG)) p = 0.f;
                            zs += p;
                            pf[4 * uk + i] = (__bf16)p;
                        }
                    }
                    if (uq == 0) zacc0 += zs; else zacc1 += zs;
                    #pragma unroll
                    for (int dt = 0; dt < 4; ++dt)
                        oacc[uq][dt] = __builtin_amdgcn_mfma_f32_16x16x32_bf16(
                            vfrag[dt], pf, oacc[uq][dt], 0, 0, 0);
                }
            }
        }
        __syncthreads();
    }
    #pragma unroll
    for (int uq = 0; uq < 2; ++uq) {
        const int q = qb + 16 * uq + r;
        #pragma unroll
        for (int dt = 0; dt < 4; ++dt) {
            float* op = Og + ((size_t)h * SEQN + q) * DVAL + 16 * dt + 4 * g;
            *(f32x4*)op = oacc[uq][dt];
        }
    }
    zacc0 += __shfl_xor(zacc0, 16); zacc0 += __shfl_xor(zacc0, 32);
    zacc1 += __shfl_xor(zacc1, 16); zacc1 += __shfl_xor(zacc1, 32);
    if (lane < 16) {
        float* zp = Og + (size_t)NHEAD * SEQN * DVAL + (size_t)h * SEQN + qb;
        zp[r] = zacc0;
        zp[16 + r] = zacc1;
    }
}

extern "C" void kernel_launch(void* const* d_in, const int* in_sizes, int n_in,
                              void* d_out, int out_size, void* d_ws, size_t ws_size,
                              hipStream_t stream) {
    const float* Q = (const float*)d_in[0];
    const float* K = (const float*)d_in[1];
    const float* V = (const float*)d_in[2];
    float* O = (float*)d_out;

    const size_t G_OFF  = 0;                       // 8*32*20480 bf16 = 10,485,760 B
    const size_t HB_OFF = 10485760;                // same size
    const size_t NEED   = 20971520;

    if (ws_size >= NEED) {
        char* ws = (char*)d_ws;
        __bf16* G  = (__bf16*)(ws + G_OFF);
        __bf16* Hb = (__bf16*)(ws + HB_OFF);
        p01_state<<<dim3(256), dim3(512), 0, stream>>>(K, V, Q, G, O);
        p2_scan  <<<dim3(160), dim3(256), 0, stream>>>(G, Hb);
        p3s_apply<<<dim3(512), dim3(256), 0, stream>>>(Q, Hb, O);
    } else {
        taylor_mono<<<dim3(512), dim3(128), 0, stream>>>(Q, K, V, O);
    }
}